// Round 8
// baseline (586.363 us; speedup 1.0000x reference)
//
#include <hip/hip_runtime.h>
#include <stdint.h>

#define NN 10000
#define NE 50000
#define KTOT 4224   // 4096 (S) + 64 (hs/bias) + 64 (h/root)
#define SPLITK 6
#define KCH 704     // KTOT / SPLITK = 22 k-steps of 32

typedef __attribute__((ext_vector_type(8))) short bf16x8;
typedef __attribute__((ext_vector_type(8))) unsigned short ushort8;
typedef __attribute__((ext_vector_type(4))) float f32x4;

__device__ __forceinline__ unsigned short f2bf(float x) {  // RNE
  unsigned int u = __float_as_uint(x);
  u += 0x7fffu + ((u >> 16) & 1u);
  return (unsigned short)(u >> 16);
}
__device__ __forceinline__ float bf2f(unsigned short h) {
  return __uint_as_float(((unsigned int)h) << 16);
}

// h = relu(x @ lin0_w + lin0_b)   [10000,20]@[20,64]
__global__ void k_lin0(const float* __restrict__ x, const float* __restrict__ w,
                       const float* __restrict__ b, float* __restrict__ h) {
  int idx = blockIdx.x * blockDim.x + threadIdx.x;
  if (idx >= NN * 64) return;
  int n = idx >> 6, o = idx & 63;
  float acc = b[o];
  const float* xr = x + n * 20;
#pragma unroll
  for (int j = 0; j < 20; ++j) acc += xr[j] * w[j * 64 + o];
  h[idx] = acc > 0.f ? acc : 0.f;
}

// u = relu(edge_attr @ nn1_w + nn1_b)   [50000,5]@[5,64]
__global__ void k_eh(const float* __restrict__ ea, const float* __restrict__ w,
                     const float* __restrict__ b, float* __restrict__ u) {
  int idx = blockIdx.x * blockDim.x + threadIdx.x;
  if (idx >= NE * 64) return;
  int e = idx >> 6, o = idx & 63;
  float acc = b[o];
  const float* er = ea + e * 5;
#pragma unroll
  for (int j = 0; j < 5; ++j) acc += er[j] * w[j * 64 + o];
  u[idx] = acc > 0.f ? acc : 0.f;
}

// edge_index arrives as int32: src = ei[0..NE), dst = ei[NE..2NE)
__global__ void k_deg(const int* __restrict__ ei, int* __restrict__ deg) {
  int e = blockIdx.x * blockDim.x + threadIdx.x;
  if (e < NE) atomicAdd(&deg[ei[NE + e]], 1);
}

// exclusive scan of deg -> offs[0..NN], plus inv_denom = 1/max(deg,1)
__global__ void k_scan(const int* __restrict__ deg, int* __restrict__ offs,
                       float* __restrict__ inv_denom) {
  __shared__ int s[256];
  int t = threadIdx.x;
  int base = t * 40;
  int sum = 0;
  for (int j = 0; j < 40; ++j) {
    int n = base + j;
    sum += (n < NN) ? deg[n] : 0;
  }
  s[t] = sum;
  __syncthreads();
  for (int off = 1; off < 256; off <<= 1) {
    int v = (t >= off) ? s[t - off] : 0;
    __syncthreads();
    s[t] += v;
    __syncthreads();
  }
  int run = s[t] - sum;  // exclusive prefix for this thread's chunk
  for (int j = 0; j < 40; ++j) {
    int n = base + j;
    if (n < NN) {
      offs[n] = run;
      int d = deg[n];
      run += d;
      inv_denom[n] = 1.0f / (float)(d > 0 ? d : 1);
    }
  }
  if (t == 255) offs[NN] = s[255];
}

__global__ void k_csr(const int* __restrict__ ei, const int* __restrict__ offs,
                      int* __restrict__ cursor, int* __restrict__ csr_src,
                      int* __restrict__ csr_eid) {
  int e = blockIdx.x * blockDim.x + threadIdx.x;
  if (e >= NE) return;
  int d = ei[NE + e];
  int pos = offs[d] + atomicAdd(&cursor[d], 1);
  csr_src[pos] = ei[e];
  csr_eid[pos] = e;
}

// WF transposed [o][k] as bf16 hi/lo planes, o=0..63, k=0..4223.
// k<4096: nn2_w; k<4160: nn2_b rows; else root_w rows.
__global__ void k_wf(const float* __restrict__ w2, const float* __restrict__ b2,
                     const float* __restrict__ rootw, unsigned short* __restrict__ wth,
                     unsigned short* __restrict__ wtl) {
  int idx = blockIdx.x * blockDim.x + threadIdx.x;
  if (idx >= 64 * KTOT) return;
  int o = idx / KTOT, c = idx - o * KTOT;
  float v;
  if (c < 4096) {
    v = w2[(c >> 6) * 4096 + (c & 63) * 64 + o];
  } else if (c < 4160) {
    v = b2[(c - 4096) * 64 + o];
  } else {
    v = rootw[(c - 4160) * 64 + o];
  }
  unsigned short h_ = f2bf(v);
  wth[idx] = h_;
  wtl[idx] = f2bf(v - bf2f(h_));
}

// Per node: SV row = [ inv_d * S(k,i) (4096) | inv_d * hs(i) (64) | h[n] (64) ]
// One WAVE per node (4 nodes/block), lane = k. Output: bf16 hi/lo planes.
__global__ void __launch_bounds__(256) k_scatter(
    const float* __restrict__ h, const float* __restrict__ u,
    const int* __restrict__ offs, const int* __restrict__ csr_src,
    const int* __restrict__ csr_eid, const float* __restrict__ inv_denom,
    unsigned short* __restrict__ svh, unsigned short* __restrict__ svl,
    int chunk_start, int chunk_nodes) {
  __shared__ float hrow_s[4][64];
  int t = threadIdx.x;
  int wid = t >> 6, lane = t & 63;
  int n_local = blockIdx.x * 4 + wid;
  if (n_local >= chunk_nodes) return;
  int n = chunk_start + n_local;
  int beg = offs[n], end = offs[n + 1];
  float invd = inv_denom[n];
  float acc[64];
#pragma unroll
  for (int i = 0; i < 64; ++i) acc[i] = 0.f;
  float hsacc = 0.f;
  int eid = 0, src = 0;
  if (beg < end) { eid = csr_eid[beg]; src = csr_src[beg]; }
  for (int c = beg; c < end; ++c) {
    float uk = u[(size_t)eid * 64 + lane];
    float hv = h[(size_t)src * 64 + lane];
    if (c + 1 < end) { eid = csr_eid[c + 1]; src = csr_src[c + 1]; }  // prefetch indices
    hrow_s[wid][lane] = hv;
    hsacc += hv;
#pragma unroll
    for (int j = 0; j < 16; ++j) {
      float4 h4 = *(const float4*)&hrow_s[wid][j * 4];
      acc[j * 4 + 0] += uk * h4.x;
      acc[j * 4 + 1] += uk * h4.y;
      acc[j * 4 + 2] += uk * h4.z;
      acc[j * 4 + 3] += uk * h4.w;
    }
  }
  size_t rowo = (size_t)n_local * KTOT + (size_t)lane * 64;
#pragma unroll
  for (int j = 0; j < 8; ++j) {
    ushort8 vh, vl;
#pragma unroll
    for (int q = 0; q < 8; ++q) {
      float xv = acc[j * 8 + q] * invd;
      unsigned short hb = f2bf(xv);
      vh[q] = hb;
      vl[q] = f2bf(xv - bf2f(hb));
    }
    *(ushort8*)(svh + rowo + j * 8) = vh;
    *(ushort8*)(svl + rowo + j * 8) = vl;
  }
  size_t base = (size_t)n_local * KTOT;
  {
    float xv = hsacc * invd;
    unsigned short hb = f2bf(xv);
    svh[base + 4096 + lane] = hb;
    svl[base + 4096 + lane] = f2bf(xv - bf2f(hb));
  }
  {
    float xv = h[(size_t)n * 64 + lane];
    unsigned short hb = f2bf(xv);
    svh[base + 4160 + lane] = hb;
    svl[base + 4160 + lane] = f2bf(xv - bf2f(hb));
  }
}

// Split-K MFMA GEMM: part[kc][node][o] = SV[node, kc*KCH..+KCH) @ WF[.,:]
// No LDS, no barriers. Block = 64 nodes x 64 out, 4 waves; wave owns a 16-row
// stripe. Per K-step(32): A frags (hi,lo) stream from HBM (lanes l,l+16,l+32,
// l+48 cover one 64B line), B frags from L2-resident wf_t. 3-pass split-bf16:
// Ah*Bh + Ah*Bl + Al*Bh -> fp32-grade accuracy, fp32 accum in MFMA.
__global__ void __launch_bounds__(256) k_mfma(
    const unsigned short* __restrict__ svh, const unsigned short* __restrict__ svl,
    const unsigned short* __restrict__ wth, const unsigned short* __restrict__ wtl,
    float* __restrict__ part, int chunk_start, int chunk_nodes) {
  int t = threadIdx.x;
  int wid = t >> 6, lane = t & 63;
  int node0 = blockIdx.x * 64;
  int kc = blockIdx.y;
  int r16 = lane & 15, kg = lane >> 4;
  int row_l = node0 + wid * 16 + r16;
  int row_g = row_l < chunk_nodes ? row_l : (chunk_nodes - 1);
  const unsigned short* pah = svh + (size_t)row_g * KTOT + kg * 8;
  const unsigned short* pal = svl + (size_t)row_g * KTOT + kg * 8;
  const unsigned short* pbh = wth + (size_t)r16 * KTOT + kg * 8;
  const unsigned short* pbl = wtl + (size_t)r16 * KTOT + kg * 8;
  f32x4 acc0 = {0.f, 0.f, 0.f, 0.f}, acc1 = acc0, acc2 = acc0, acc3 = acc0;
#pragma unroll 1
  for (int ks = 0; ks < KCH / 32; ++ks) {
    int kb = kc * KCH + ks * 32;
    bf16x8 ah = *(const bf16x8*)(pah + kb);
    bf16x8 al = *(const bf16x8*)(pal + kb);
    bf16x8 bh0 = *(const bf16x8*)(pbh + kb);
    bf16x8 bh1 = *(const bf16x8*)(pbh + (size_t)16 * KTOT + kb);
    bf16x8 bh2 = *(const bf16x8*)(pbh + (size_t)32 * KTOT + kb);
    bf16x8 bh3 = *(const bf16x8*)(pbh + (size_t)48 * KTOT + kb);
    bf16x8 bl0 = *(const bf16x8*)(pbl + kb);
    bf16x8 bl1 = *(const bf16x8*)(pbl + (size_t)16 * KTOT + kb);
    bf16x8 bl2 = *(const bf16x8*)(pbl + (size_t)32 * KTOT + kb);
    bf16x8 bl3 = *(const bf16x8*)(pbl + (size_t)48 * KTOT + kb);
    acc0 = __builtin_amdgcn_mfma_f32_16x16x32_bf16(ah, bh0, acc0, 0, 0, 0);
    acc1 = __builtin_amdgcn_mfma_f32_16x16x32_bf16(ah, bh1, acc1, 0, 0, 0);
    acc2 = __builtin_amdgcn_mfma_f32_16x16x32_bf16(ah, bh2, acc2, 0, 0, 0);
    acc3 = __builtin_amdgcn_mfma_f32_16x16x32_bf16(ah, bh3, acc3, 0, 0, 0);
    acc0 = __builtin_amdgcn_mfma_f32_16x16x32_bf16(ah, bl0, acc0, 0, 0, 0);
    acc1 = __builtin_amdgcn_mfma_f32_16x16x32_bf16(ah, bl1, acc1, 0, 0, 0);
    acc2 = __builtin_amdgcn_mfma_f32_16x16x32_bf16(ah, bl2, acc2, 0, 0, 0);
    acc3 = __builtin_amdgcn_mfma_f32_16x16x32_bf16(ah, bl3, acc3, 0, 0, 0);
    acc0 = __builtin_amdgcn_mfma_f32_16x16x32_bf16(al, bh0, acc0, 0, 0, 0);
    acc1 = __builtin_amdgcn_mfma_f32_16x16x32_bf16(al, bh1, acc1, 0, 0, 0);
    acc2 = __builtin_amdgcn_mfma_f32_16x16x32_bf16(al, bh2, acc2, 0, 0, 0);
    acc3 = __builtin_amdgcn_mfma_f32_16x16x32_bf16(al, bh3, acc3, 0, 0, 0);
  }
  // C/D layout: col = lane&15, row = (lane>>4)*4 + reg  [m89]
  float* pp = part + (size_t)kc * NN * 64 +
              (size_t)(chunk_start + node0 + wid * 16) * 64;
  int rbase = kg * 4;
#pragma unroll
  for (int j = 0; j < 4; ++j) {
    int row = rbase + j;
    if (node0 + wid * 16 + row < chunk_nodes) {
      pp[row * 64 + 0  + r16] = acc0[j];
      pp[row * 64 + 16 + r16] = acc1[j];
      pp[row * 64 + 32 + r16] = acc2[j];
      pp[row * 64 + 48 + r16] = acc3[j];
    }
  }
}

// h_new = relu(sum_k part + conv_b)
__global__ void k_epi(const float* __restrict__ part, const float* __restrict__ cb,
                      float* __restrict__ hout) {
  int idx = blockIdx.x * blockDim.x + threadIdx.x;
  if (idx >= NN * 64) return;
  int o = idx & 63;
  float acc = cb[o];
#pragma unroll
  for (int kc = 0; kc < SPLITK; ++kc) acc += part[(size_t)kc * NN * 64 + idx];
  hout[idx] = acc > 0.f ? acc : 0.f;
}

// partial node-sum: part[160][64]
__global__ void k_sum_p(const float* __restrict__ h, float* __restrict__ part) {
  __shared__ float s[256];
  int t = threadIdx.x, b = blockIdx.x;
  int o = t & 63, g = t >> 6;
  float acc = 0.f;
  for (int k = 0;; ++k) {
    int n = b + 160 * (g + 4 * k);
    if (n >= NN) break;
    acc += h[(size_t)n * 64 + o];
  }
  s[t] = acc;
  __syncthreads();
  if (t < 64) part[(size_t)b * 64 + t] = s[t] + s[64 + t] + s[128 + t] + s[192 + t];
}

// reduce partials -> concat -> bneck (69 -> 384), one block of 384
__global__ void __launch_bounds__(384) k_bneck(
    const float* __restrict__ part, const float* __restrict__ vpa,
    const float* __restrict__ mz, const float* __restrict__ adduct,
    const float* __restrict__ bw, const float* __restrict__ bb,
    float* __restrict__ aout) {
  __shared__ float in69[69];
  __shared__ float red[256];
  int t = threadIdx.x;
  if (t < 256) {
    int o = t & 63, g = t >> 6;
    float acc = 0.f;
    for (int k = 0; k < 40; ++k) acc += part[(size_t)(g * 40 + k) * 64 + o];
    red[t] = acc;
  }
  __syncthreads();
  if (t < 64) in69[t] = red[t] + red[64 + t] + red[128 + t] + red[192 + t];
  if (t == 64) in69[64] = vpa[0];
  if (t == 65) in69[65] = mz[0];
  if (t >= 66 && t < 69) in69[t] = adduct[t - 66];
  __syncthreads();
  float acc = bb[t];
#pragma unroll 4
  for (int i = 0; i < 69; ++i) acc += in69[i] * bw[i * 384 + t];
  aout[t] = acc > 0.f ? acc : 0.f;
}

// one 384->384 relu layer, 24 blocks x 256 threads, 16 outputs/block
__global__ void __launch_bounds__(256) k_layer(
    const float* __restrict__ ain, const float* __restrict__ w,
    const float* __restrict__ bias, float* __restrict__ aout) {
  __shared__ float a_s[384];
  __shared__ float red[256];
  int t = threadIdx.x;
  for (int i = t; i < 384; i += 256) a_s[i] = ain[i];
  __syncthreads();
  int o = blockIdx.x * 16 + (t & 15);
  int ig = t >> 4;  // 0..15
  float acc = 0.f;
#pragma unroll
  for (int k = 0; k < 24; ++k) {
    int i = ig + (k << 4);
    acc += a_s[i] * w[i * 384 + o];
  }
  red[t] = acc;
  __syncthreads();
  if (t < 128) red[t] += red[t + 128];
  __syncthreads();
  if (t < 64) red[t] += red[t + 64];
  __syncthreads();
  if (t < 32) red[t] += red[t + 32];
  __syncthreads();
  if (t < 16) {
    float v = red[t] + red[t + 16] + bias[o];
    aout[o] = v > 0.f ? v : 0.f;
  }
}

// final: act @ l2w + l2b -> scalar
__global__ void __launch_bounds__(384) k_out(
    const float* __restrict__ act, const float* __restrict__ l2w,
    const float* __restrict__ l2b, float* __restrict__ out) {
  __shared__ float red[384];
  int t = threadIdx.x;
  red[t] = act[t] * l2w[t];
  __syncthreads();
  if (t < 128) red[t] += red[t + 128] + red[t + 256];
  __syncthreads();
  if (t < 64) {
    float s2 = red[t] + red[t + 64];
#pragma unroll
    for (int off = 32; off; off >>= 1) s2 += __shfl_down(s2, off);
    if (t == 0) out[0] = s2 + l2b[0];
  }
}

extern "C" void kernel_launch(void* const* d_in, const int* in_sizes, int n_in,
                              void* d_out, int out_size, void* d_ws, size_t ws_size,
                              hipStream_t stream) {
  const float* x      = (const float*)d_in[0];
  const int* ei       = (const int*)d_in[1];   // int32 on device
  const float* ea     = (const float*)d_in[2];
  const float* vpa    = (const float*)d_in[3];
  const float* mz     = (const float*)d_in[4];
  const float* adduct = (const float*)d_in[5];
  const float* lin0_w = (const float*)d_in[6];
  const float* lin0_b = (const float*)d_in[7];
  const float* nn1_w  = (const float*)d_in[8];
  const float* nn1_b  = (const float*)d_in[9];
  const float* nn2_w  = (const float*)d_in[10];
  const float* nn2_b  = (const float*)d_in[11];
  const float* root_w = (const float*)d_in[12];
  const float* conv_b = (const float*)d_in[13];
  const float* bw     = (const float*)d_in[14];
  const float* bb     = (const float*)d_in[15];
  const float* l1w    = (const float*)d_in[16];
  const float* l1b    = (const float*)d_in[17];
  const float* l2w    = (const float*)d_in[18];
  const float* l2b    = (const float*)d_in[19];

  char* p = (char*)d_ws;
  auto alloc = [&](size_t bytes) {
    char* r = p;
    p += (bytes + 255) & ~(size_t)255;
    return r;
  };
  float* h0      = (float*)alloc((size_t)NN * 64 * 4);
  float* h1      = (float*)alloc((size_t)NN * 64 * 4);
  float* u       = (float*)alloc((size_t)NE * 64 * 4);
  unsigned short* wth = (unsigned short*)alloc((size_t)64 * KTOT * 2);
  unsigned short* wtl = (unsigned short*)alloc((size_t)64 * KTOT * 2);
  int* deg       = (int*)alloc(NN * 4);
  int* offs      = (int*)alloc((NN + 1) * 4);
  int* cursor    = (int*)alloc(NN * 4);
  float* invd    = (float*)alloc(NN * 4);
  int* csr_src   = (int*)alloc(NE * 4);
  int* csr_eid   = (int*)alloc(NE * 4);
  float* part    = (float*)alloc(160 * 64 * 4);
  float* kpart   = (float*)alloc((size_t)SPLITK * NN * 64 * 4);
  float* actA    = (float*)alloc(384 * 4);
  float* actB    = (float*)alloc(384 * 4);
  size_t used = (size_t)(p - (char*)d_ws);
  size_t avail = ws_size > used ? ws_size - used : 0;
  long long CH = (long long)(avail / ((size_t)KTOT * 4));  // 2 bf16 planes = 4 B/elem
  if (CH > NN) CH = NN;
  if (CH < 1) CH = 1;
  unsigned short* svh = (unsigned short*)p;
  unsigned short* svl = svh + (size_t)CH * KTOT;

  hipMemsetAsync(deg, 0, NN * 4, stream);
  hipMemsetAsync(cursor, 0, NN * 4, stream);

  k_lin0<<<(NN * 64 + 255) / 256, 256, 0, stream>>>(x, lin0_w, lin0_b, h0);
  k_eh<<<(NE * 64 + 255) / 256, 256, 0, stream>>>(ea, nn1_w, nn1_b, u);
  k_deg<<<(NE + 255) / 256, 256, 0, stream>>>(ei, deg);
  k_scan<<<1, 256, 0, stream>>>(deg, offs, invd);
  k_csr<<<(NE + 255) / 256, 256, 0, stream>>>(ei, offs, cursor, csr_src, csr_eid);
  k_wf<<<(64 * KTOT + 255) / 256, 256, 0, stream>>>(nn2_w, nn2_b, root_w, wth, wtl);

  float* hc = h0;
  float* hn = h1;
  for (int it = 0; it < 3; ++it) {
    for (int cs = 0; cs < NN; cs += (int)CH) {
      int cn = (NN - cs < (int)CH) ? (NN - cs) : (int)CH;
      k_scatter<<<(cn + 3) / 4, 256, 0, stream>>>(hc, u, offs, csr_src, csr_eid,
                                                  invd, svh, svl, cs, cn);
      dim3 g2((cn + 63) / 64, SPLITK);
      k_mfma<<<g2, 256, 0, stream>>>(svh, svl, wth, wtl, kpart, cs, cn);
    }
    k_epi<<<(NN * 64 + 255) / 256, 256, 0, stream>>>(kpart, conv_b, hn);
    float* tmp = hc; hc = hn; hn = tmp;
  }
  k_sum_p<<<160, 256, 0, stream>>>(hc, part);
  k_bneck<<<1, 384, 0, stream>>>(part, vpa, mz, adduct, bw, bb, actA);
  float* ain = actA;
  float* aout = actB;
  for (int L = 0; L < 6; ++L) {
    k_layer<<<24, 256, 0, stream>>>(ain, l1w, l1b, aout);
    float* tmp = ain; ain = aout; aout = tmp;
  }
  k_out<<<1, 384, 0, stream>>>(ain, l2w, l2b, (float*)d_out);
}